// Round 1
// baseline (525.697 us; speedup 1.0000x reference)
//
#include <hip/hip_runtime.h>
#include <hip/hip_bf16.h>

using bf16 = __hip_bfloat16;

typedef float floatx4 __attribute__((ext_vector_type(4)));
typedef short shortx8 __attribute__((ext_vector_type(8)));
typedef __bf16 bf16x8 __attribute__((ext_vector_type(8)));

#define NEG_BIG -3.0e38f

// async global->LDS DMA, 16 B per lane; LDS dest = wave-uniform base + lane*16
#define GLOAD_LDS16(g, l)                                                     \
  __builtin_amdgcn_global_load_lds(                                           \
      (const __attribute__((address_space(1))) unsigned int*)(g),             \
      (__attribute__((address_space(3))) unsigned int*)(l), 16, 0, 0)

__device__ __forceinline__ float bf2f(short s) {
  union { unsigned int u; float f; } x;
  x.u = ((unsigned int)(unsigned short)s) << 16;
  return x.f;
}

// ---------------- dtype sniff: cos[0]==1.0 exactly.
// fp32 -> word0 = 0x3F800000 ; bf16 -> word0 = 0x3F803F80 (two packed 1.0's)
__global__ void sniff_k(const void* __restrict__ cosp, int* __restrict__ flag) {
  unsigned w = *(const unsigned*)cosp;
  *flag = (w == 0x3F800000u) ? 1 : 0;  // 1 = inputs are fp32
}

// ---------------- generic input -> bf16 convert, vectorized x8 ----------------
__global__ void conv_k(const void* __restrict__ src, bf16* __restrict__ dst, int n8,
                       const int* __restrict__ flag) {
  int i = blockIdx.x * blockDim.x + threadIdx.x;
  if (i >= n8) return;
  shortx8 r;
  if (*flag) {
    const float4* s4 = (const float4*)src;
    float4 x0 = s4[i * 2], x1 = s4[i * 2 + 1];
    float xs[8] = {x0.x, x0.y, x0.z, x0.w, x1.x, x1.y, x1.z, x1.w};
#pragma unroll
    for (int e = 0; e < 8; ++e)
      r[e] = (short)__bfloat16_as_ushort(__float2bfloat16(xs[e]));
  } else {
    r = ((const shortx8*)src)[i];
  }
  *(shortx8*)(dst + (size_t)i * 8) = r;
}

// ---------------- fused convert + transpose: src (2048, C) -> dst (C, 2048) bf16 ------
__global__ void transpose_conv_k(const void* __restrict__ src, bf16* __restrict__ dst,
                                 int C, const int* __restrict__ flag) {
  __shared__ bf16 tile[32][33];
  int fp32 = *flag;
  int tx = threadIdx.x, ty = threadIdx.y;
  int c0 = blockIdx.x * 32, r0 = blockIdx.y * 32;
#pragma unroll
  for (int i = 0; i < 32; i += 8) {
    size_t idx = (size_t)(r0 + ty + i) * C + c0 + tx;
    tile[ty + i][tx] = fp32 ? __float2bfloat16(((const float*)src)[idx])
                            : ((const bf16*)src)[idx];
  }
  __syncthreads();
#pragma unroll
  for (int i = 0; i < 32; i += 8)
    dst[(size_t)(c0 + ty + i) * 2048 + r0 + tx] = tile[tx][ty + i];
}

// ---------------- GEMM: C(M,N) = A(M,K) @ Bt(N,K)^T, bf16 in, fp32 acc ----------------
// m97-style staging: global_load_lds width=16 into UNPADDED [128][32] LDS tiles.
#define BM 128
#define BN 128
#define BK 32

__global__ __launch_bounds__(256) void gemm_bt(const bf16* __restrict__ A,
                                               const bf16* __restrict__ Bt,
                                               void* __restrict__ Cp,
                                               int M, int N, int K,
                                               const int* __restrict__ flag,
                                               int f32out_en) {
  __shared__ __align__(16) short sA[BM][BK];
  __shared__ __align__(16) short sB[BN][BK];
  const int f32out = f32out_en ? *flag : 0;
  const int tid = threadIdx.x;
  const int wave = tid >> 6, lane = tid & 63;
  const int wr = wave >> 1, wc = wave & 1;
  const int lrow = lane & 15, quad = lane >> 4;
  const int m0 = blockIdx.y * BM, n0 = blockIdx.x * BN;

  floatx4 acc[4][4];
#pragma unroll
  for (int r = 0; r < 4; ++r)
#pragma unroll
    for (int c = 0; c < 4; ++c)
      acc[r][c] = (floatx4){0.f, 0.f, 0.f, 0.f};

  const int l4r = lane >> 2;        // 0..15: row within wave chunk
  const int l4c = (lane & 3) * 8;   // col segment (8 bf16 = 16 B)
  const bf16* gA0 = A  + (size_t)(m0 + wave * 16 + l4r) * K + l4c;
  const bf16* gA1 = gA0 + (size_t)64 * K;
  const bf16* gB0 = Bt + (size_t)(n0 + wave * 16 + l4r) * K + l4c;
  const bf16* gB1 = gB0 + (size_t)64 * K;
  short* ldsA0 = &sA[wave * 16][0];
  short* ldsA1 = &sA[64 + wave * 16][0];
  short* ldsB0 = &sB[wave * 16][0];
  short* ldsB1 = &sB[64 + wave * 16][0];

  for (int kk = 0; kk < K; kk += BK) {
    GLOAD_LDS16(gA0 + kk, ldsA0);
    GLOAD_LDS16(gA1 + kk, ldsA1);
    GLOAD_LDS16(gB0 + kk, ldsB0);
    GLOAD_LDS16(gB1 + kk, ldsB1);
    __syncthreads();  // drains vmcnt (DMA complete) + barrier

    bf16x8 af[4], bfr[4];
#pragma unroll
    for (int r = 0; r < 4; ++r)
      af[r] = __builtin_bit_cast(bf16x8, *(const shortx8*)&sA[wr * 64 + r * 16 + lrow][quad * 8]);
#pragma unroll
    for (int c = 0; c < 4; ++c)
      bfr[c] = __builtin_bit_cast(bf16x8, *(const shortx8*)&sB[wc * 64 + c * 16 + lrow][quad * 8]);
#pragma unroll
    for (int r = 0; r < 4; ++r)
#pragma unroll
      for (int c = 0; c < 4; ++c)
        acc[r][c] = __builtin_amdgcn_mfma_f32_16x16x32_bf16(af[r], bfr[c], acc[r][c], 0, 0, 0);
    __syncthreads();
  }

#pragma unroll
  for (int r = 0; r < 4; ++r) {
#pragma unroll
    for (int c = 0; c < 4; ++c) {
      int mrow = m0 + wr * 64 + r * 16 + quad * 4;
      int ncol = n0 + wc * 64 + c * 16 + lrow;
      if (f32out) {
#pragma unroll
        for (int i = 0; i < 4; ++i)
          ((float*)Cp)[(size_t)(mrow + i) * N + ncol] = acc[r][c][i];
      } else {
#pragma unroll
        for (int i = 0; i < 4; ++i)
          ((bf16*)Cp)[(size_t)(mrow + i) * N + ncol] = __float2bfloat16(acc[r][c][i]);
      }
    }
  }
}

// ---------------- RoPE in-place on q (heads 0..31) and k (kv heads 0..7) ----------------
// Vectorized: each thread rotates 8 contiguous elements of the low half + the
// matching 8 of the high half of one 64-wide head (shortx8 loads, G13).
__global__ void rope_k(bf16* __restrict__ qkv, const bf16* __restrict__ cosb,
                       const bf16* __restrict__ sinb) {
  int idx = blockIdx.x * blockDim.x + threadIdx.x;  // 4096*40*4 = 655360
  int i8 = (idx & 3) * 8;
  int head = (idx >> 2) % 40;
  int m = idx / 160;
  if (m >= 4096) return;
  int p = m & 2047;
  size_t base = (size_t)m * 3072 + (head < 32 ? head * 64 : 2048 + (head - 32) * 64);
  shortx8 a8 = *(const shortx8*)(qkv + base + i8);
  shortx8 b8 = *(const shortx8*)(qkv + base + 32 + i8);
  const bf16* cp = cosb + p * 64 + i8;
  const bf16* sp = sinb + p * 64 + i8;
  shortx8 c0 = *(const shortx8*)cp;
  shortx8 s0 = *(const shortx8*)sp;
  shortx8 c1 = *(const shortx8*)(cp + 32);
  shortx8 s1 = *(const shortx8*)(sp + 32);
  shortx8 ra, rb;
#pragma unroll
  for (int e = 0; e < 8; ++e) {
    float a = bf2f(a8[e]), bb = bf2f(b8[e]);
    ra[e] = (short)__bfloat16_as_ushort(__float2bfloat16(a * bf2f(c0[e]) - bb * bf2f(s0[e])));
    rb[e] = (short)__bfloat16_as_ushort(__float2bfloat16(bb * bf2f(c1[e]) + a * bf2f(s1[e])));
  }
  *(shortx8*)(qkv + base + i8) = ra;
  *(shortx8*)(qkv + base + 32 + i8) = rb;
}

// ---------------- flash attention (causal, GQA 4:1) — MFMA, 128-row Q-tile ----------
// One q-tile per block; grid (16,32,2) = 1024 blocks = 4 blocks/CU all-resident
// (2x the previous 512-block paired layout). Per-CU load stays uniform CU-aware:
// blocks i and i+256 share a CU under linear / XCD-round-robin dispatch
// (grid.x*grid.y = 512 % 256 == 0), so (bx, h) gets qt=bx and (bx, h+16) gets
// qt=15-bx -> every CU sums to 72 kv-iters. Q is pre-scaled by 0.125 (exact in
// bf16) so the per-tile 32-mul score scaling disappears.
__global__ __launch_bounds__(256, 4) void attn_k(const bf16* __restrict__ qkv,
                                                 bf16* __restrict__ O) {
  const int S = 2048, LDQ = 3072, D = 2048;
  const int h = blockIdx.y, b = blockIdx.z;
  const int qt = (h >= 16) ? (15 - (int)blockIdx.x) : (int)blockIdx.x;
  const int kvh = h >> 2;
  const int tid = threadIdx.x;
  const int w = tid >> 6, lane = tid & 63;
  const int quad = lane >> 4, l15 = lane & 15;

  __shared__ __align__(16) short sK [64][72];    // [kv pos][hd]
  __shared__ __align__(16) short sVt[64][72];    // [hd][swizzled kv pos]
  __shared__ __align__(16) short sP [4][32][72]; // per-wave P round-trip (32 rows)

  const int srow = tid >> 2, sseg = (tid & 3) * 16;
  const bf16* kvbase = qkv + (size_t)(b * S) * LDQ + 2048 + kvh * 64 + sseg;

  const int q0 = qt * 128;

  // Q fragments: 2 sub-tiles x 2 k-halves, pre-scaled by 1/sqrt(64)
  bf16x8 qa[2][2];
#pragma unroll
  for (int mt = 0; mt < 2; ++mt) {
    const bf16* qp = qkv + (size_t)(b * S + q0 + w * 32 + mt * 16 + l15) * LDQ + h * 64 + quad * 8;
    qa[mt][0] = __builtin_bit_cast(bf16x8, *(const shortx8*)qp);
    qa[mt][1] = __builtin_bit_cast(bf16x8, *(const shortx8*)(qp + 32));
  }
#pragma unroll
  for (int mt = 0; mt < 2; ++mt)
#pragma unroll
    for (int kk = 0; kk < 2; ++kk)
#pragma unroll
      for (int e = 0; e < 8; ++e)
        qa[mt][kk][e] = (__bf16)((float)qa[mt][kk][e] * 0.125f);

  floatx4 oacc[2][4];
  float m_i[2][4], l_p[2][4];
#pragma unroll
  for (int mt = 0; mt < 2; ++mt) {
#pragma unroll
    for (int d = 0; d < 4; ++d) oacc[mt][d] = (floatx4){0.f, 0.f, 0.f, 0.f};
#pragma unroll
    for (int i = 0; i < 4; ++i) { m_i[mt][i] = NEG_BIG; l_p[mt][i] = 0.f; }
  }

  const int jtEnd = 2 * qt + 2;
  // prefetch tile 0
  const bf16* kp = kvbase + (size_t)srow * LDQ;
  int4 kr0 = *(const int4*)kp;
  int4 kr1 = *(const int4*)(kp + 8);
  int4 vr0 = *(const int4*)(kp + 512);
  int4 vr1 = *(const int4*)(kp + 520);

  for (int jt = 0; jt < jtEnd; ++jt) {
    // ---- stage prefetched K (row layout) and V (transposed, bank-swizzled) ----
    *(int4*)&sK[srow][sseg]     = kr0;
    *(int4*)&sK[srow][sseg + 8] = kr1;
    {
      const short* v0s = (const short*)&vr0;
      const short* v1s = (const short*)&vr1;
#pragma unroll
      for (int e = 0; e < 8; ++e) {
        int d = sseg + e;
        sVt[d][(srow + (d & 56)) & 63] = v0s[e];
      }
#pragma unroll
      for (int e = 0; e < 8; ++e) {
        int d = sseg + 8 + e;
        sVt[d][(srow + (d & 56)) & 63] = v1s[e];
      }
    }
    if (jt + 1 < jtEnd) {
      const bf16* kp2 = kvbase + (size_t)((jt + 1) * 64 + srow) * LDQ;
      kr0 = *(const int4*)kp2;
      kr1 = *(const int4*)(kp2 + 8);
      vr0 = *(const int4*)(kp2 + 512);
      vr1 = *(const int4*)(kp2 + 520);
    }
    __syncthreads();

    // ---- S = Q K^T: 32x64 per wave; K B-frags loaded once, shared by both mt ----
    floatx4 sfr[2][4];
#pragma unroll
    for (int mt = 0; mt < 2; ++mt)
#pragma unroll
      for (int nb = 0; nb < 4; ++nb) sfr[mt][nb] = (floatx4){0.f, 0.f, 0.f, 0.f};
#pragma unroll
    for (int kk = 0; kk < 2; ++kk) {
#pragma unroll
      for (int nb = 0; nb < 4; ++nb) {
        bf16x8 bfr = __builtin_bit_cast(bf16x8,
            *(const shortx8*)&sK[nb * 16 + l15][kk * 32 + quad * 8]);
        sfr[0][nb] = __builtin_amdgcn_mfma_f32_16x16x32_bf16(qa[0][kk], bfr, sfr[0][nb], 0, 0, 0);
        sfr[1][nb] = __builtin_amdgcn_mfma_f32_16x16x32_bf16(qa[1][kk], bfr, sfr[1][nb], 0, 0, 0);
      }
    }

    // ---- per sub-tile: mask, online softmax, P store, O rescale ----
#pragma unroll
    for (int mt = 0; mt < 2; ++mt) {
      float sc[4][4];
#pragma unroll
      for (int nb = 0; nb < 4; ++nb)
#pragma unroll
        for (int i = 0; i < 4; ++i) sc[nb][i] = sfr[mt][nb][i];
      if (jt >= 2 * qt) {  // only the two diagonal-crossing tiles need masking
#pragma unroll
        for (int nb = 0; nb < 4; ++nb) {
          int jg = jt * 64 + nb * 16 + l15;
#pragma unroll
          for (int i = 0; i < 4; ++i) {
            int rg = q0 + w * 32 + mt * 16 + quad * 4 + i;
            if (jg > rg) sc[nb][i] = NEG_BIG;
          }
        }
      }

      float alpha[4];
#pragma unroll
      for (int i = 0; i < 4; ++i) {
        float m = fmaxf(fmaxf(sc[0][i], sc[1][i]), fmaxf(sc[2][i], sc[3][i]));
        m = fmaxf(m, __shfl_xor(m, 1));
        m = fmaxf(m, __shfl_xor(m, 2));
        m = fmaxf(m, __shfl_xor(m, 4));
        m = fmaxf(m, __shfl_xor(m, 8));
        float Mn = fmaxf(m_i[mt][i], m);
        alpha[i] = __expf(m_i[mt][i] - Mn);
        m_i[mt][i] = Mn;
      }
      float rs[4] = {0.f, 0.f, 0.f, 0.f};
#pragma unroll
      for (int nb = 0; nb < 4; ++nb)
#pragma unroll
        for (int i = 0; i < 4; ++i) {
          float pv = __expf(sc[nb][i] - m_i[mt][i]);
          rs[i] += pv;
          sP[w][mt * 16 + quad * 4 + i][nb * 16 + l15] =
              (short)__bfloat16_as_ushort(__float2bfloat16(pv));
        }
#pragma unroll
      for (int i = 0; i < 4; ++i) l_p[mt][i] = l_p[mt][i] * alpha[i] + rs[i];
#pragma unroll
      for (int d = 0; d < 4; ++d)
#pragma unroll
        for (int i = 0; i < 4; ++i) oacc[mt][d][i] *= alpha[i];
    }

    // ---- O += P V: V^T B-frags loaded once, shared by both mt ----
#pragma unroll
    for (int kk = 0; kk < 2; ++kk) {
      bf16x8 af0 = __builtin_bit_cast(bf16x8,
          *(const shortx8*)&sP[w][l15][kk * 32 + quad * 8]);
      bf16x8 af1 = __builtin_bit_cast(bf16x8,
          *(const shortx8*)&sP[w][16 + l15][kk * 32 + quad * 8]);
#pragma unroll
      for (int db = 0; db < 4; ++db) {
        int row = db * 16 + l15;
        int col = (kk * 32 + quad * 8 + (row & 56)) & 63;
        bf16x8 bfr = __builtin_bit_cast(bf16x8, *(const shortx8*)&sVt[row][col]);
        oacc[0][db] = __builtin_amdgcn_mfma_f32_16x16x32_bf16(af0, bfr, oacc[0][db], 0, 0, 0);
        oacc[1][db] = __builtin_amdgcn_mfma_f32_16x16x32_bf16(af1, bfr, oacc[1][db], 0, 0, 0);
      }
    }
    __syncthreads();  // before next tile overwrites sK/sVt
  }

  // ---- epilogue: reduce lane-partial l across the quad, store O rows ----
#pragma unroll
  for (int mt = 0; mt < 2; ++mt) {
#pragma unroll
    for (int i = 0; i < 4; ++i) {
      float l = l_p[mt][i];
      l += __shfl_xor(l, 1);
      l += __shfl_xor(l, 2);
      l += __shfl_xor(l, 4);
      l += __shfl_xor(l, 8);
      float inv = 1.f / l;
      bf16* op = O + (size_t)(b * S + q0 + w * 32 + mt * 16 + quad * 4 + i) * D + h * 64 + l15;
#pragma unroll
      for (int d = 0; d < 4; ++d)
        op[d * 16] = __float2bfloat16(oacc[mt][d][i] * inv);
    }
  }
}

// ---------------- launch ----------------
// ws layout (bf16 elements from ws16 = d_ws + 16; flag int at d_ws):
//   xb 8.4M | cosb/sinb 131k | bt_qkv 6.3M | wot 4.2M | qkv 12.6M  (~63.4 MB)
extern "C" void kernel_launch(void* const* d_in, const int* in_sizes, int n_in,
                              void* d_out, int out_size, void* d_ws, size_t ws_size,
                              hipStream_t stream) {
  const void* x    = d_in[0];
  const void* cosp = d_in[1];
  const void* sinp = d_in[2];
  const void* wq   = d_in[3];
  const void* wk   = d_in[4];
  const void* wv   = d_in[5];
  const void* wo   = d_in[6];

  int* flag = (int*)d_ws;
  bf16* ws16 = (bf16*)((char*)d_ws + 16);
  bf16* xb     = ws16;
  bf16* cosb   = xb + (size_t)8388608;
  bf16* sinb   = cosb + 131072;
  bf16* bt_qkv = sinb + 131072;
  bf16* wot    = bt_qkv + (size_t)3072 * 2048;
  bf16* qkv    = wot + (size_t)2048 * 2048;
  bf16* o      = xb;  // x dead after QKV GEMM; attn output reuses it

  sniff_k<<<1, 1, 0, stream>>>(cosp, flag);

  conv_k<<<(1048576 + 255) / 256, 256, 0, stream>>>(x, xb, 1048576, flag);
  conv_k<<<(16384 + 255) / 256, 256, 0, stream>>>(cosp, cosb, 16384, flag);
  conv_k<<<(16384 + 255) / 256, 256, 0, stream>>>(sinp, sinb, 16384, flag);

  dim3 tb(32, 8);
  transpose_conv_k<<<dim3(64, 64), tb, 0, stream>>>(wq, bt_qkv, 2048, flag);
  transpose_conv_k<<<dim3(16, 64), tb, 0, stream>>>(wk, bt_qkv + (size_t)2048 * 2048, 512, flag);
  transpose_conv_k<<<dim3(16, 64), tb, 0, stream>>>(wv, bt_qkv + (size_t)2560 * 2048, 512, flag);
  transpose_conv_k<<<dim3(64, 64), tb, 0, stream>>>(wo, wot, 2048, flag);

  // QKV projection: (4096,2048) @ (2048,3072), bf16 out
  gemm_bt<<<dim3(3072 / BN, 4096 / BM), 256, 0, stream>>>(xb, bt_qkv, qkv,
                                                          4096, 3072, 2048, flag, 0);

  rope_k<<<2560, 256, 0, stream>>>(qkv, cosb, sinb);

  // attention: one 128-row q-tile per block; CU-aware complementary qt mapping
  attn_k<<<dim3(16, 32, 2), 256, 0, stream>>>(qkv, o);

  // output projection: (4096,2048) @ (2048,2048); output dtype follows input dtype
  gemm_bt<<<dim3(2048 / BN, 4096 / BM), 256, 0, stream>>>(o, wot, d_out,
                                                          4096, 2048, 2048, flag, 1);
}

// Round 2
// 448.470 us; speedup vs baseline: 1.1722x; 1.1722x over previous
//
#include <hip/hip_runtime.h>
#include <hip/hip_bf16.h>

using bf16 = __hip_bfloat16;

typedef float floatx4 __attribute__((ext_vector_type(4)));
typedef short shortx8 __attribute__((ext_vector_type(8)));
typedef __bf16 bf16x8 __attribute__((ext_vector_type(8)));

#define NEG_BIG -3.0e38f

// async global->LDS DMA, 16 B per lane; LDS dest = wave-uniform base + lane*16
#define GLOAD_LDS16(g, l)                                                     \
  __builtin_amdgcn_global_load_lds(                                           \
      (const __attribute__((address_space(1))) unsigned int*)(g),             \
      (__attribute__((address_space(3))) unsigned int*)(l), 16, 0, 0)

__device__ __forceinline__ float bf2f(short s) {
  union { unsigned int u; float f; } x;
  x.u = ((unsigned int)(unsigned short)s) << 16;
  return x.f;
}

// ---------------- dtype sniff: cos[0]==1.0 exactly.
// fp32 -> word0 = 0x3F800000 ; bf16 -> word0 = 0x3F803F80 (two packed 1.0's)
__global__ void sniff_k(const void* __restrict__ cosp, int* __restrict__ flag) {
  unsigned w = *(const unsigned*)cosp;
  *flag = (w == 0x3F800000u) ? 1 : 0;  // 1 = inputs are fp32
}

// ---------------- generic input -> bf16 convert, vectorized x8 ----------------
__global__ void conv_k(const void* __restrict__ src, bf16* __restrict__ dst, int n8,
                       const int* __restrict__ flag) {
  int i = blockIdx.x * blockDim.x + threadIdx.x;
  if (i >= n8) return;
  shortx8 r;
  if (*flag) {
    const float4* s4 = (const float4*)src;
    float4 x0 = s4[i * 2], x1 = s4[i * 2 + 1];
    float xs[8] = {x0.x, x0.y, x0.z, x0.w, x1.x, x1.y, x1.z, x1.w};
#pragma unroll
    for (int e = 0; e < 8; ++e)
      r[e] = (short)__bfloat16_as_ushort(__float2bfloat16(xs[e]));
  } else {
    r = ((const shortx8*)src)[i];
  }
  *(shortx8*)(dst + (size_t)i * 8) = r;
}

// ---------------- fused convert + transpose: src (2048, C) -> dst (C, 2048) bf16 ------
__global__ void transpose_conv_k(const void* __restrict__ src, bf16* __restrict__ dst,
                                 int C, const int* __restrict__ flag) {
  __shared__ bf16 tile[32][33];
  int fp32 = *flag;
  int tx = threadIdx.x, ty = threadIdx.y;
  int c0 = blockIdx.x * 32, r0 = blockIdx.y * 32;
#pragma unroll
  for (int i = 0; i < 32; i += 8) {
    size_t idx = (size_t)(r0 + ty + i) * C + c0 + tx;
    tile[ty + i][tx] = fp32 ? __float2bfloat16(((const float*)src)[idx])
                            : ((const bf16*)src)[idx];
  }
  __syncthreads();
#pragma unroll
  for (int i = 0; i < 32; i += 8)
    dst[(size_t)(c0 + ty + i) * 2048 + r0 + tx] = tile[tx][ty + i];
}

// ---------------- GEMM: C(M,N) = A(M,K) @ Bt(N,K)^T, bf16 in, fp32 acc ----------------
// m97-style staging: global_load_lds width=16 into UNPADDED [128][32] LDS tiles.
#define BM 128
#define BN 128
#define BK 32

__global__ __launch_bounds__(256) void gemm_bt(const bf16* __restrict__ A,
                                               const bf16* __restrict__ Bt,
                                               void* __restrict__ Cp,
                                               int M, int N, int K,
                                               const int* __restrict__ flag,
                                               int f32out_en) {
  __shared__ __align__(16) short sA[BM][BK];
  __shared__ __align__(16) short sB[BN][BK];
  const int f32out = f32out_en ? *flag : 0;
  const int tid = threadIdx.x;
  const int wave = tid >> 6, lane = tid & 63;
  const int wr = wave >> 1, wc = wave & 1;
  const int lrow = lane & 15, quad = lane >> 4;
  const int m0 = blockIdx.y * BM, n0 = blockIdx.x * BN;

  floatx4 acc[4][4];
#pragma unroll
  for (int r = 0; r < 4; ++r)
#pragma unroll
    for (int c = 0; c < 4; ++c)
      acc[r][c] = (floatx4){0.f, 0.f, 0.f, 0.f};

  const int l4r = lane >> 2;        // 0..15: row within wave chunk
  const int l4c = (lane & 3) * 8;   // col segment (8 bf16 = 16 B)
  const bf16* gA0 = A  + (size_t)(m0 + wave * 16 + l4r) * K + l4c;
  const bf16* gA1 = gA0 + (size_t)64 * K;
  const bf16* gB0 = Bt + (size_t)(n0 + wave * 16 + l4r) * K + l4c;
  const bf16* gB1 = gB0 + (size_t)64 * K;
  short* ldsA0 = &sA[wave * 16][0];
  short* ldsA1 = &sA[64 + wave * 16][0];
  short* ldsB0 = &sB[wave * 16][0];
  short* ldsB1 = &sB[64 + wave * 16][0];

  for (int kk = 0; kk < K; kk += BK) {
    GLOAD_LDS16(gA0 + kk, ldsA0);
    GLOAD_LDS16(gA1 + kk, ldsA1);
    GLOAD_LDS16(gB0 + kk, ldsB0);
    GLOAD_LDS16(gB1 + kk, ldsB1);
    __syncthreads();  // drains vmcnt (DMA complete) + barrier

    bf16x8 af[4], bfr[4];
#pragma unroll
    for (int r = 0; r < 4; ++r)
      af[r] = __builtin_bit_cast(bf16x8, *(const shortx8*)&sA[wr * 64 + r * 16 + lrow][quad * 8]);
#pragma unroll
    for (int c = 0; c < 4; ++c)
      bfr[c] = __builtin_bit_cast(bf16x8, *(const shortx8*)&sB[wc * 64 + c * 16 + lrow][quad * 8]);
#pragma unroll
    for (int r = 0; r < 4; ++r)
#pragma unroll
      for (int c = 0; c < 4; ++c)
        acc[r][c] = __builtin_amdgcn_mfma_f32_16x16x32_bf16(af[r], bfr[c], acc[r][c], 0, 0, 0);
    __syncthreads();
  }

#pragma unroll
  for (int r = 0; r < 4; ++r) {
#pragma unroll
    for (int c = 0; c < 4; ++c) {
      int mrow = m0 + wr * 64 + r * 16 + quad * 4;
      int ncol = n0 + wc * 64 + c * 16 + lrow;
      if (f32out) {
#pragma unroll
        for (int i = 0; i < 4; ++i)
          ((float*)Cp)[(size_t)(mrow + i) * N + ncol] = acc[r][c][i];
      } else {
#pragma unroll
        for (int i = 0; i < 4; ++i)
          ((bf16*)Cp)[(size_t)(mrow + i) * N + ncol] = __float2bfloat16(acc[r][c][i]);
      }
    }
  }
}

// ---------------- RoPE in-place on q (heads 0..31) and k (kv heads 0..7) ----------------
// Vectorized: each thread rotates 8 contiguous elements of the low half + the
// matching 8 of the high half of one 64-wide head (shortx8 loads, G13).
__global__ void rope_k(bf16* __restrict__ qkv, const bf16* __restrict__ cosb,
                       const bf16* __restrict__ sinb) {
  int idx = blockIdx.x * blockDim.x + threadIdx.x;  // 4096*40*4 = 655360
  int i8 = (idx & 3) * 8;
  int head = (idx >> 2) % 40;
  int m = idx / 160;
  if (m >= 4096) return;
  int p = m & 2047;
  size_t base = (size_t)m * 3072 + (head < 32 ? head * 64 : 2048 + (head - 32) * 64);
  shortx8 a8 = *(const shortx8*)(qkv + base + i8);
  shortx8 b8 = *(const shortx8*)(qkv + base + 32 + i8);
  const bf16* cp = cosb + p * 64 + i8;
  const bf16* sp = sinb + p * 64 + i8;
  shortx8 c0 = *(const shortx8*)cp;
  shortx8 s0 = *(const shortx8*)sp;
  shortx8 c1 = *(const shortx8*)(cp + 32);
  shortx8 s1 = *(const shortx8*)(sp + 32);
  shortx8 ra, rb;
#pragma unroll
  for (int e = 0; e < 8; ++e) {
    float a = bf2f(a8[e]), bb = bf2f(b8[e]);
    ra[e] = (short)__bfloat16_as_ushort(__float2bfloat16(a * bf2f(c0[e]) - bb * bf2f(s0[e])));
    rb[e] = (short)__bfloat16_as_ushort(__float2bfloat16(bb * bf2f(c1[e]) + a * bf2f(s1[e])));
  }
  *(shortx8*)(qkv + base + i8) = ra;
  *(shortx8*)(qkv + base + 32 + i8) = rb;
}

// ---------------- flash attention (causal, GQA 4:1) — MFMA, 128-row Q-tile ----------
// One q-tile per block; grid (16,32,2) = 1024 blocks = 4 blocks/CU all-resident.
// NOTE: plain __launch_bounds__(256) — the (256,4) min-waves hint forced the
// register allocator down to 64 VGPRs and spilled ~250 MB of scratch through HBM
// (R1 post-mortem: WRITE_SIZE 16->166 MB, attn 124->213 us). At the natural 116
// VGPRs the HW already fits 4 waves/SIMD (116<=128), so 4 blocks/CU needs no hint.
// Per-CU load stays uniform CU-aware: blocks i and i+256 share a CU under linear /
// XCD-round-robin dispatch (grid.x*grid.y = 512 % 256 == 0), so (bx, h) gets qt=bx
// and (bx, h+16) gets qt=15-bx -> every CU sums to 72 kv-iters. Q is pre-scaled by
// 0.125 (exact in bf16) so the per-tile 32-mul score scaling disappears.
__global__ __launch_bounds__(256) void attn_k(const bf16* __restrict__ qkv,
                                              bf16* __restrict__ O) {
  const int S = 2048, LDQ = 3072, D = 2048;
  const int h = blockIdx.y, b = blockIdx.z;
  const int qt = (h >= 16) ? (15 - (int)blockIdx.x) : (int)blockIdx.x;
  const int kvh = h >> 2;
  const int tid = threadIdx.x;
  const int w = tid >> 6, lane = tid & 63;
  const int quad = lane >> 4, l15 = lane & 15;

  __shared__ __align__(16) short sK [64][72];    // [kv pos][hd]
  __shared__ __align__(16) short sVt[64][72];    // [hd][swizzled kv pos]
  __shared__ __align__(16) short sP [4][32][72]; // per-wave P round-trip (32 rows)

  const int srow = tid >> 2, sseg = (tid & 3) * 16;
  const bf16* kvbase = qkv + (size_t)(b * S) * LDQ + 2048 + kvh * 64 + sseg;

  const int q0 = qt * 128;

  // Q fragments: 2 sub-tiles x 2 k-halves, pre-scaled by 1/sqrt(64)
  bf16x8 qa[2][2];
#pragma unroll
  for (int mt = 0; mt < 2; ++mt) {
    const bf16* qp = qkv + (size_t)(b * S + q0 + w * 32 + mt * 16 + l15) * LDQ + h * 64 + quad * 8;
    qa[mt][0] = __builtin_bit_cast(bf16x8, *(const shortx8*)qp);
    qa[mt][1] = __builtin_bit_cast(bf16x8, *(const shortx8*)(qp + 32));
  }
#pragma unroll
  for (int mt = 0; mt < 2; ++mt)
#pragma unroll
    for (int kk = 0; kk < 2; ++kk)
#pragma unroll
      for (int e = 0; e < 8; ++e)
        qa[mt][kk][e] = (__bf16)((float)qa[mt][kk][e] * 0.125f);

  floatx4 oacc[2][4];
  float m_i[2][4], l_p[2][4];
#pragma unroll
  for (int mt = 0; mt < 2; ++mt) {
#pragma unroll
    for (int d = 0; d < 4; ++d) oacc[mt][d] = (floatx4){0.f, 0.f, 0.f, 0.f};
#pragma unroll
    for (int i = 0; i < 4; ++i) { m_i[mt][i] = NEG_BIG; l_p[mt][i] = 0.f; }
  }

  const int jtEnd = 2 * qt + 2;
  // prefetch tile 0
  const bf16* kp = kvbase + (size_t)srow * LDQ;
  int4 kr0 = *(const int4*)kp;
  int4 kr1 = *(const int4*)(kp + 8);
  int4 vr0 = *(const int4*)(kp + 512);
  int4 vr1 = *(const int4*)(kp + 520);

  for (int jt = 0; jt < jtEnd; ++jt) {
    // ---- stage prefetched K (row layout) and V (transposed, bank-swizzled) ----
    *(int4*)&sK[srow][sseg]     = kr0;
    *(int4*)&sK[srow][sseg + 8] = kr1;
    {
      const short* v0s = (const short*)&vr0;
      const short* v1s = (const short*)&vr1;
#pragma unroll
      for (int e = 0; e < 8; ++e) {
        int d = sseg + e;
        sVt[d][(srow + (d & 56)) & 63] = v0s[e];
      }
#pragma unroll
      for (int e = 0; e < 8; ++e) {
        int d = sseg + 8 + e;
        sVt[d][(srow + (d & 56)) & 63] = v1s[e];
      }
    }
    if (jt + 1 < jtEnd) {
      const bf16* kp2 = kvbase + (size_t)((jt + 1) * 64 + srow) * LDQ;
      kr0 = *(const int4*)kp2;
      kr1 = *(const int4*)(kp2 + 8);
      vr0 = *(const int4*)(kp2 + 512);
      vr1 = *(const int4*)(kp2 + 520);
    }
    __syncthreads();

    // ---- S = Q K^T: 32x64 per wave; K B-frags loaded once, shared by both mt ----
    floatx4 sfr[2][4];
#pragma unroll
    for (int mt = 0; mt < 2; ++mt)
#pragma unroll
      for (int nb = 0; nb < 4; ++nb) sfr[mt][nb] = (floatx4){0.f, 0.f, 0.f, 0.f};
#pragma unroll
    for (int kk = 0; kk < 2; ++kk) {
#pragma unroll
      for (int nb = 0; nb < 4; ++nb) {
        bf16x8 bfr = __builtin_bit_cast(bf16x8,
            *(const shortx8*)&sK[nb * 16 + l15][kk * 32 + quad * 8]);
        sfr[0][nb] = __builtin_amdgcn_mfma_f32_16x16x32_bf16(qa[0][kk], bfr, sfr[0][nb], 0, 0, 0);
        sfr[1][nb] = __builtin_amdgcn_mfma_f32_16x16x32_bf16(qa[1][kk], bfr, sfr[1][nb], 0, 0, 0);
      }
    }

    // ---- per sub-tile: mask, online softmax, P store, O rescale ----
#pragma unroll
    for (int mt = 0; mt < 2; ++mt) {
      float sc[4][4];
#pragma unroll
      for (int nb = 0; nb < 4; ++nb)
#pragma unroll
        for (int i = 0; i < 4; ++i) sc[nb][i] = sfr[mt][nb][i];
      if (jt >= 2 * qt) {  // only the two diagonal-crossing tiles need masking
#pragma unroll
        for (int nb = 0; nb < 4; ++nb) {
          int jg = jt * 64 + nb * 16 + l15;
#pragma unroll
          for (int i = 0; i < 4; ++i) {
            int rg = q0 + w * 32 + mt * 16 + quad * 4 + i;
            if (jg > rg) sc[nb][i] = NEG_BIG;
          }
        }
      }

      float alpha[4];
#pragma unroll
      for (int i = 0; i < 4; ++i) {
        float m = fmaxf(fmaxf(sc[0][i], sc[1][i]), fmaxf(sc[2][i], sc[3][i]));
        m = fmaxf(m, __shfl_xor(m, 1));
        m = fmaxf(m, __shfl_xor(m, 2));
        m = fmaxf(m, __shfl_xor(m, 4));
        m = fmaxf(m, __shfl_xor(m, 8));
        float Mn = fmaxf(m_i[mt][i], m);
        alpha[i] = __expf(m_i[mt][i] - Mn);
        m_i[mt][i] = Mn;
      }
      float rs[4] = {0.f, 0.f, 0.f, 0.f};
#pragma unroll
      for (int nb = 0; nb < 4; ++nb)
#pragma unroll
        for (int i = 0; i < 4; ++i) {
          float pv = __expf(sc[nb][i] - m_i[mt][i]);
          rs[i] += pv;
          sP[w][mt * 16 + quad * 4 + i][nb * 16 + l15] =
              (short)__bfloat16_as_ushort(__float2bfloat16(pv));
        }
#pragma unroll
      for (int i = 0; i < 4; ++i) l_p[mt][i] = l_p[mt][i] * alpha[i] + rs[i];
#pragma unroll
      for (int d = 0; d < 4; ++d)
#pragma unroll
        for (int i = 0; i < 4; ++i) oacc[mt][d][i] *= alpha[i];
    }

    // ---- O += P V: V^T B-frags loaded once, shared by both mt ----
#pragma unroll
    for (int kk = 0; kk < 2; ++kk) {
      bf16x8 af0 = __builtin_bit_cast(bf16x8,
          *(const shortx8*)&sP[w][l15][kk * 32 + quad * 8]);
      bf16x8 af1 = __builtin_bit_cast(bf16x8,
          *(const shortx8*)&sP[w][16 + l15][kk * 32 + quad * 8]);
#pragma unroll
      for (int db = 0; db < 4; ++db) {
        int row = db * 16 + l15;
        int col = (kk * 32 + quad * 8 + (row & 56)) & 63;
        bf16x8 bfr = __builtin_bit_cast(bf16x8, *(const shortx8*)&sVt[row][col]);
        oacc[0][db] = __builtin_amdgcn_mfma_f32_16x16x32_bf16(af0, bfr, oacc[0][db], 0, 0, 0);
        oacc[1][db] = __builtin_amdgcn_mfma_f32_16x16x32_bf16(af1, bfr, oacc[1][db], 0, 0, 0);
      }
    }
    __syncthreads();  // before next tile overwrites sK/sVt
  }

  // ---- epilogue: reduce lane-partial l across the quad, store O rows ----
#pragma unroll
  for (int mt = 0; mt < 2; ++mt) {
#pragma unroll
    for (int i = 0; i < 4; ++i) {
      float l = l_p[mt][i];
      l += __shfl_xor(l, 1);
      l += __shfl_xor(l, 2);
      l += __shfl_xor(l, 4);
      l += __shfl_xor(l, 8);
      float inv = 1.f / l;
      bf16* op = O + (size_t)(b * S + q0 + w * 32 + mt * 16 + quad * 4 + i) * D + h * 64 + l15;
#pragma unroll
      for (int d = 0; d < 4; ++d)
        op[d * 16] = __float2bfloat16(oacc[mt][d][i] * inv);
    }
  }
}

// ---------------- launch ----------------
// ws layout (bf16 elements from ws16 = d_ws + 16; flag int at d_ws):
//   xb 8.4M | cosb/sinb 131k | bt_qkv 6.3M | wot 4.2M | qkv 12.6M  (~63.4 MB)
extern "C" void kernel_launch(void* const* d_in, const int* in_sizes, int n_in,
                              void* d_out, int out_size, void* d_ws, size_t ws_size,
                              hipStream_t stream) {
  const void* x    = d_in[0];
  const void* cosp = d_in[1];
  const void* sinp = d_in[2];
  const void* wq   = d_in[3];
  const void* wk   = d_in[4];
  const void* wv   = d_in[5];
  const void* wo   = d_in[6];

  int* flag = (int*)d_ws;
  bf16* ws16 = (bf16*)((char*)d_ws + 16);
  bf16* xb     = ws16;
  bf16* cosb   = xb + (size_t)8388608;
  bf16* sinb   = cosb + 131072;
  bf16* bt_qkv = sinb + 131072;
  bf16* wot    = bt_qkv + (size_t)3072 * 2048;
  bf16* qkv    = wot + (size_t)2048 * 2048;
  bf16* o      = xb;  // x dead after QKV GEMM; attn output reuses it

  sniff_k<<<1, 1, 0, stream>>>(cosp, flag);

  conv_k<<<(1048576 + 255) / 256, 256, 0, stream>>>(x, xb, 1048576, flag);
  conv_k<<<(16384 + 255) / 256, 256, 0, stream>>>(cosp, cosb, 16384, flag);
  conv_k<<<(16384 + 255) / 256, 256, 0, stream>>>(sinp, sinb, 16384, flag);

  dim3 tb(32, 8);
  transpose_conv_k<<<dim3(64, 64), tb, 0, stream>>>(wq, bt_qkv, 2048, flag);
  transpose_conv_k<<<dim3(16, 64), tb, 0, stream>>>(wk, bt_qkv + (size_t)2048 * 2048, 512, flag);
  transpose_conv_k<<<dim3(16, 64), tb, 0, stream>>>(wv, bt_qkv + (size_t)2560 * 2048, 512, flag);
  transpose_conv_k<<<dim3(64, 64), tb, 0, stream>>>(wo, wot, 2048, flag);

  // QKV projection: (4096,2048) @ (2048,3072), bf16 out
  gemm_bt<<<dim3(3072 / BN, 4096 / BM), 256, 0, stream>>>(xb, bt_qkv, qkv,
                                                          4096, 3072, 2048, flag, 0);

  rope_k<<<2560, 256, 0, stream>>>(qkv, cosb, sinb);

  // attention: one 128-row q-tile per block; CU-aware complementary qt mapping
  attn_k<<<dim3(16, 32, 2), 256, 0, stream>>>(qkv, o);

  // output projection: (4096,2048) @ (2048,2048); output dtype follows input dtype
  gemm_bt<<<dim3(2048 / BN, 4096 / BM), 256, 0, stream>>>(o, wot, d_out,
                                                          4096, 2048, 2048, flag, 1);
}

// Round 3
// 420.861 us; speedup vs baseline: 1.2491x; 1.0656x over previous
//
#include <hip/hip_runtime.h>
#include <hip/hip_bf16.h>

using bf16 = __hip_bfloat16;

typedef float floatx4 __attribute__((ext_vector_type(4)));
typedef short shortx8 __attribute__((ext_vector_type(8)));
typedef __bf16 bf16x8 __attribute__((ext_vector_type(8)));

#define NEG_BIG -3.0e38f

// async global->LDS DMA, 16 B per lane; LDS dest = wave-uniform base + lane*16
#define GLOAD_LDS16(g, l)                                                     \
  __builtin_amdgcn_global_load_lds(                                           \
      (const __attribute__((address_space(1))) unsigned int*)(g),             \
      (__attribute__((address_space(3))) unsigned int*)(l), 16, 0, 0)

__device__ __forceinline__ float bf2f(short s) {
  union { unsigned int u; float f; } x;
  x.u = ((unsigned int)(unsigned short)s) << 16;
  return x.f;
}

// ---------------- dtype sniff: cos[0]==1.0 exactly.
// fp32 -> word0 = 0x3F800000 ; bf16 -> word0 = 0x3F803F80 (two packed 1.0's)
__global__ void sniff_k(const void* __restrict__ cosp, int* __restrict__ flag) {
  unsigned w = *(const unsigned*)cosp;
  *flag = (w == 0x3F800000u) ? 1 : 0;  // 1 = inputs are fp32
}

// ---------------- generic input -> bf16 convert, vectorized x8 ----------------
__global__ void conv_k(const void* __restrict__ src, bf16* __restrict__ dst, int n8,
                       const int* __restrict__ flag) {
  int i = blockIdx.x * blockDim.x + threadIdx.x;
  if (i >= n8) return;
  shortx8 r;
  if (*flag) {
    const float4* s4 = (const float4*)src;
    float4 x0 = s4[i * 2], x1 = s4[i * 2 + 1];
    float xs[8] = {x0.x, x0.y, x0.z, x0.w, x1.x, x1.y, x1.z, x1.w};
#pragma unroll
    for (int e = 0; e < 8; ++e)
      r[e] = (short)__bfloat16_as_ushort(__float2bfloat16(xs[e]));
  } else {
    r = ((const shortx8*)src)[i];
  }
  *(shortx8*)(dst + (size_t)i * 8) = r;
}

// ---------------- fused convert + transpose: src (2048, C) -> dst (C, 2048) bf16 ------
__global__ void transpose_conv_k(const void* __restrict__ src, bf16* __restrict__ dst,
                                 int C, const int* __restrict__ flag) {
  __shared__ bf16 tile[32][33];
  int fp32 = *flag;
  int tx = threadIdx.x, ty = threadIdx.y;
  int c0 = blockIdx.x * 32, r0 = blockIdx.y * 32;
#pragma unroll
  for (int i = 0; i < 32; i += 8) {
    size_t idx = (size_t)(r0 + ty + i) * C + c0 + tx;
    tile[ty + i][tx] = fp32 ? __float2bfloat16(((const float*)src)[idx])
                            : ((const bf16*)src)[idx];
  }
  __syncthreads();
#pragma unroll
  for (int i = 0; i < 32; i += 8)
    dst[(size_t)(c0 + ty + i) * 2048 + r0 + tx] = tile[tx][ty + i];
}

// ---------------- GEMM: C(M,N) = A(M,K) @ Bt(N,K)^T, bf16 in, fp32 acc ----------------
// m97-style staging: global_load_lds width=16 into UNPADDED [128][32] LDS tiles.
#define BM 128
#define BN 128
#define BK 32

__global__ __launch_bounds__(256) void gemm_bt(const bf16* __restrict__ A,
                                               const bf16* __restrict__ Bt,
                                               void* __restrict__ Cp,
                                               int M, int N, int K,
                                               const int* __restrict__ flag,
                                               int f32out_en) {
  __shared__ __align__(16) short sA[BM][BK];
  __shared__ __align__(16) short sB[BN][BK];
  const int f32out = f32out_en ? *flag : 0;
  const int tid = threadIdx.x;
  const int wave = tid >> 6, lane = tid & 63;
  const int wr = wave >> 1, wc = wave & 1;
  const int lrow = lane & 15, quad = lane >> 4;
  const int m0 = blockIdx.y * BM, n0 = blockIdx.x * BN;

  floatx4 acc[4][4];
#pragma unroll
  for (int r = 0; r < 4; ++r)
#pragma unroll
    for (int c = 0; c < 4; ++c)
      acc[r][c] = (floatx4){0.f, 0.f, 0.f, 0.f};

  const int l4r = lane >> 2;        // 0..15: row within wave chunk
  const int l4c = (lane & 3) * 8;   // col segment (8 bf16 = 16 B)
  const bf16* gA0 = A  + (size_t)(m0 + wave * 16 + l4r) * K + l4c;
  const bf16* gA1 = gA0 + (size_t)64 * K;
  const bf16* gB0 = Bt + (size_t)(n0 + wave * 16 + l4r) * K + l4c;
  const bf16* gB1 = gB0 + (size_t)64 * K;
  short* ldsA0 = &sA[wave * 16][0];
  short* ldsA1 = &sA[64 + wave * 16][0];
  short* ldsB0 = &sB[wave * 16][0];
  short* ldsB1 = &sB[64 + wave * 16][0];

  for (int kk = 0; kk < K; kk += BK) {
    GLOAD_LDS16(gA0 + kk, ldsA0);
    GLOAD_LDS16(gA1 + kk, ldsA1);
    GLOAD_LDS16(gB0 + kk, ldsB0);
    GLOAD_LDS16(gB1 + kk, ldsB1);
    __syncthreads();  // drains vmcnt (DMA complete) + barrier

    bf16x8 af[4], bfr[4];
#pragma unroll
    for (int r = 0; r < 4; ++r)
      af[r] = __builtin_bit_cast(bf16x8, *(const shortx8*)&sA[wr * 64 + r * 16 + lrow][quad * 8]);
#pragma unroll
    for (int c = 0; c < 4; ++c)
      bfr[c] = __builtin_bit_cast(bf16x8, *(const shortx8*)&sB[wc * 64 + c * 16 + lrow][quad * 8]);
#pragma unroll
    for (int r = 0; r < 4; ++r)
#pragma unroll
      for (int c = 0; c < 4; ++c)
        acc[r][c] = __builtin_amdgcn_mfma_f32_16x16x32_bf16(af[r], bfr[c], acc[r][c], 0, 0, 0);
    __syncthreads();
  }

#pragma unroll
  for (int r = 0; r < 4; ++r) {
#pragma unroll
    for (int c = 0; c < 4; ++c) {
      int mrow = m0 + wr * 64 + r * 16 + quad * 4;
      int ncol = n0 + wc * 64 + c * 16 + lrow;
      if (f32out) {
#pragma unroll
        for (int i = 0; i < 4; ++i)
          ((float*)Cp)[(size_t)(mrow + i) * N + ncol] = acc[r][c][i];
      } else {
#pragma unroll
        for (int i = 0; i < 4; ++i)
          ((bf16*)Cp)[(size_t)(mrow + i) * N + ncol] = __float2bfloat16(acc[r][c][i]);
      }
    }
  }
}

// ---------------- RoPE in-place on q (heads 0..31) and k (kv heads 0..7) ----------------
__global__ void rope_k(bf16* __restrict__ qkv, const bf16* __restrict__ cosb,
                       const bf16* __restrict__ sinb) {
  int idx = blockIdx.x * blockDim.x + threadIdx.x;  // 4096*40*4 = 655360
  int i8 = (idx & 3) * 8;
  int head = (idx >> 2) % 40;
  int m = idx / 160;
  if (m >= 4096) return;
  int p = m & 2047;
  size_t base = (size_t)m * 3072 + (head < 32 ? head * 64 : 2048 + (head - 32) * 64);
  shortx8 a8 = *(const shortx8*)(qkv + base + i8);
  shortx8 b8 = *(const shortx8*)(qkv + base + 32 + i8);
  const bf16* cp = cosb + p * 64 + i8;
  const bf16* sp = sinb + p * 64 + i8;
  shortx8 c0 = *(const shortx8*)cp;
  shortx8 s0 = *(const shortx8*)sp;
  shortx8 c1 = *(const shortx8*)(cp + 32);
  shortx8 s1 = *(const shortx8*)(sp + 32);
  shortx8 ra, rb;
#pragma unroll
  for (int e = 0; e < 8; ++e) {
    float a = bf2f(a8[e]), bb = bf2f(b8[e]);
    ra[e] = (short)__bfloat16_as_ushort(__float2bfloat16(a * bf2f(c0[e]) - bb * bf2f(s0[e])));
    rb[e] = (short)__bfloat16_as_ushort(__float2bfloat16(bb * bf2f(c1[e]) + a * bf2f(s1[e])));
  }
  *(shortx8*)(qkv + base + i8) = ra;
  *(shortx8*)(qkv + base + 32 + i8) = rb;
}

// ---------------- V pre-transpose: qkv V region -> Vt[b][kvh][d][kv], rotation fused ---
// Vt[(b*8+kvh)*64 + d][jt*64 + c] = V[b][kv = jt*64 + ((c - (d&56)) & 63)][kvh][d].
// The per-64-tile rotation (kv + (d&56)) & 63 is the attn sVt bank-stagger; fusing it
// here lets attn stage V with 2 linear ds_write_b128 per lane (m173 pre-swizzle
// pattern: swizzle the SOURCE, keep the LDS write linear, read with the swizzle).
__global__ void vt_k(const bf16* __restrict__ qkv, bf16* __restrict__ Vt) {
  __shared__ __align__(16) short tile[64][72];
  const int jt = blockIdx.x, kvh = blockIdx.y, b = blockIdx.z;
  const int t = threadIdx.x;
  const int r = t >> 2, seg = (t & 3) * 16;
  const bf16* src = qkv + (size_t)(b * 2048 + jt * 64 + r) * 3072 + 2560 + kvh * 64 + seg;
  *(int4*)&tile[r][seg]     = *(const int4*)src;
  *(int4*)&tile[r][seg + 8] = *(const int4*)(src + 8);
  __syncthreads();
  bf16* dst = Vt + ((size_t)(b * 8 + kvh) * 64 + r) * 2048 + jt * 64 + seg;
  short out[16];
#pragma unroll
  for (int e = 0; e < 16; ++e)
    out[e] = tile[(seg + e - (r & 56)) & 63][r];
  *(int4*)dst       = *(int4*)&out[0];
  *(int4*)(dst + 8) = *(int4*)&out[8];
}

// ---------------- flash attention (causal, GQA 4:1) — MFMA, 128-row Q-tile ----------
// R2 post-mortem: uniform work per block is mandatory — co-residency-based balancing
// (1024 variable-work blocks) dropped time-avg occupancy to 15% and cost +22 us.
// Back to the known-good 512-block grid: each block runs qt=p then qt=15-p (34
// kv-iters, constant). V is staged from the pre-transposed+pre-rotated Vt with 2
// ds_write_b128/lane (was 32 scalar ds_write_b16 + swizzle math); PV read path and
// its bank-stagger formula are unchanged. Q pre-scaled by 0.125 (exact in bf16).
// Plain __launch_bounds__(256): the (256,4) hint forced 64 VGPR and ~250 MB of
// scratch spill (R1).
__global__ __launch_bounds__(256) void attn_k(const bf16* __restrict__ qkv,
                                              const bf16* __restrict__ Vt,
                                              bf16* __restrict__ O) {
  const int S = 2048, LDQ = 3072, D = 2048;
  const int p = blockIdx.x, h = blockIdx.y, b = blockIdx.z;
  const int kvh = h >> 2;
  const int tid = threadIdx.x;
  const int w = tid >> 6, lane = tid & 63;
  const int quad = lane >> 4, l15 = lane & 15;

  __shared__ __align__(16) short sK [64][72];    // [kv pos][hd]
  __shared__ __align__(16) short sVt[64][72];    // [hd][rotated kv pos]
  __shared__ __align__(16) short sP [4][32][72]; // per-wave P round-trip (32 rows)

  const int srow = tid >> 2, sseg = (tid & 3) * 16;
  // K staging: srow = kv row, sseg = hd offset
  const bf16* kbase = qkv + (size_t)(b * S) * LDQ + 2048 + kvh * 64 + sseg;
  // V staging: srow = hd row, sseg = (rotated) kv offset within the 64-tile
  const bf16* vbase = Vt + ((size_t)(b * 8 + kvh) * 64 + srow) * 2048 + sseg;

  for (int phase = 0; phase < 2; ++phase) {
    const int qt = phase ? (15 - p) : p;
    const int q0 = qt * 128;

    // Q fragments: 2 sub-tiles x 2 k-halves, pre-scaled by 1/sqrt(64)
    bf16x8 qa[2][2];
#pragma unroll
    for (int mt = 0; mt < 2; ++mt) {
      const bf16* qp = qkv + (size_t)(b * S + q0 + w * 32 + mt * 16 + l15) * LDQ + h * 64 + quad * 8;
      qa[mt][0] = __builtin_bit_cast(bf16x8, *(const shortx8*)qp);
      qa[mt][1] = __builtin_bit_cast(bf16x8, *(const shortx8*)(qp + 32));
    }
#pragma unroll
    for (int mt = 0; mt < 2; ++mt)
#pragma unroll
      for (int kk = 0; kk < 2; ++kk)
#pragma unroll
        for (int e = 0; e < 8; ++e)
          qa[mt][kk][e] = (__bf16)((float)qa[mt][kk][e] * 0.125f);

    floatx4 oacc[2][4];
    float m_i[2][4], l_p[2][4];
#pragma unroll
    for (int mt = 0; mt < 2; ++mt) {
#pragma unroll
      for (int d = 0; d < 4; ++d) oacc[mt][d] = (floatx4){0.f, 0.f, 0.f, 0.f};
#pragma unroll
      for (int i = 0; i < 4; ++i) { m_i[mt][i] = NEG_BIG; l_p[mt][i] = 0.f; }
    }

    const int jtEnd = 2 * qt + 2;
    // prefetch tile 0
    const bf16* kp = kbase + (size_t)srow * LDQ;
    int4 kr0 = *(const int4*)kp;
    int4 kr1 = *(const int4*)(kp + 8);
    int4 vr0 = *(const int4*)vbase;
    int4 vr1 = *(const int4*)(vbase + 8);

    for (int jt = 0; jt < jtEnd; ++jt) {
      // ---- stage prefetched K (row layout) and V (pre-rotated, vector writes) ----
      *(int4*)&sK[srow][sseg]      = kr0;
      *(int4*)&sK[srow][sseg + 8]  = kr1;
      *(int4*)&sVt[srow][sseg]     = vr0;
      *(int4*)&sVt[srow][sseg + 8] = vr1;
      if (jt + 1 < jtEnd) {
        const bf16* kp2 = kbase + (size_t)((jt + 1) * 64 + srow) * LDQ;
        kr0 = *(const int4*)kp2;
        kr1 = *(const int4*)(kp2 + 8);
        const bf16* vp2 = vbase + (jt + 1) * 64;
        vr0 = *(const int4*)vp2;
        vr1 = *(const int4*)(vp2 + 8);
      }
      __syncthreads();

      // ---- S = Q K^T: 32x64 per wave; K B-frags loaded once, shared by both mt ----
      floatx4 sfr[2][4];
#pragma unroll
      for (int mt = 0; mt < 2; ++mt)
#pragma unroll
        for (int nb = 0; nb < 4; ++nb) sfr[mt][nb] = (floatx4){0.f, 0.f, 0.f, 0.f};
#pragma unroll
      for (int kk = 0; kk < 2; ++kk) {
#pragma unroll
        for (int nb = 0; nb < 4; ++nb) {
          bf16x8 bfr = __builtin_bit_cast(bf16x8,
              *(const shortx8*)&sK[nb * 16 + l15][kk * 32 + quad * 8]);
          sfr[0][nb] = __builtin_amdgcn_mfma_f32_16x16x32_bf16(qa[0][kk], bfr, sfr[0][nb], 0, 0, 0);
          sfr[1][nb] = __builtin_amdgcn_mfma_f32_16x16x32_bf16(qa[1][kk], bfr, sfr[1][nb], 0, 0, 0);
        }
      }

      // ---- per sub-tile: mask, online softmax, P store, O rescale ----
#pragma unroll
      for (int mt = 0; mt < 2; ++mt) {
        float sc[4][4];
#pragma unroll
        for (int nb = 0; nb < 4; ++nb)
#pragma unroll
          for (int i = 0; i < 4; ++i) sc[nb][i] = sfr[mt][nb][i];
        if (jt >= 2 * qt) {  // only the two diagonal-crossing tiles need masking
#pragma unroll
          for (int nb = 0; nb < 4; ++nb) {
            int jg = jt * 64 + nb * 16 + l15;
#pragma unroll
            for (int i = 0; i < 4; ++i) {
              int rg = q0 + w * 32 + mt * 16 + quad * 4 + i;
              if (jg > rg) sc[nb][i] = NEG_BIG;
            }
          }
        }

        float alpha[4];
#pragma unroll
        for (int i = 0; i < 4; ++i) {
          float m = fmaxf(fmaxf(sc[0][i], sc[1][i]), fmaxf(sc[2][i], sc[3][i]));
          m = fmaxf(m, __shfl_xor(m, 1));
          m = fmaxf(m, __shfl_xor(m, 2));
          m = fmaxf(m, __shfl_xor(m, 4));
          m = fmaxf(m, __shfl_xor(m, 8));
          float Mn = fmaxf(m_i[mt][i], m);
          alpha[i] = __expf(m_i[mt][i] - Mn);
          m_i[mt][i] = Mn;
        }
        float rs[4] = {0.f, 0.f, 0.f, 0.f};
#pragma unroll
        for (int nb = 0; nb < 4; ++nb)
#pragma unroll
          for (int i = 0; i < 4; ++i) {
            float pv = __expf(sc[nb][i] - m_i[mt][i]);
            rs[i] += pv;
            sP[w][mt * 16 + quad * 4 + i][nb * 16 + l15] =
                (short)__bfloat16_as_ushort(__float2bfloat16(pv));
          }
#pragma unroll
        for (int i = 0; i < 4; ++i) l_p[mt][i] = l_p[mt][i] * alpha[i] + rs[i];
#pragma unroll
        for (int d = 0; d < 4; ++d)
#pragma unroll
          for (int i = 0; i < 4; ++i) oacc[mt][d][i] *= alpha[i];
      }

      // ---- O += P V: V^T B-frags loaded once, shared by both mt ----
#pragma unroll
      for (int kk = 0; kk < 2; ++kk) {
        bf16x8 af0 = __builtin_bit_cast(bf16x8,
            *(const shortx8*)&sP[w][l15][kk * 32 + quad * 8]);
        bf16x8 af1 = __builtin_bit_cast(bf16x8,
            *(const shortx8*)&sP[w][16 + l15][kk * 32 + quad * 8]);
#pragma unroll
        for (int db = 0; db < 4; ++db) {
          int row = db * 16 + l15;
          int col = (kk * 32 + quad * 8 + (row & 56)) & 63;
          bf16x8 bfr = __builtin_bit_cast(bf16x8, *(const shortx8*)&sVt[row][col]);
          oacc[0][db] = __builtin_amdgcn_mfma_f32_16x16x32_bf16(af0, bfr, oacc[0][db], 0, 0, 0);
          oacc[1][db] = __builtin_amdgcn_mfma_f32_16x16x32_bf16(af1, bfr, oacc[1][db], 0, 0, 0);
        }
      }
      __syncthreads();  // before next tile overwrites sK/sVt
    }

    // ---- epilogue: reduce lane-partial l across the quad, store O rows ----
#pragma unroll
    for (int mt = 0; mt < 2; ++mt) {
#pragma unroll
      for (int i = 0; i < 4; ++i) {
        float l = l_p[mt][i];
        l += __shfl_xor(l, 1);
        l += __shfl_xor(l, 2);
        l += __shfl_xor(l, 4);
        l += __shfl_xor(l, 8);
        float inv = 1.f / l;
        bf16* op = O + (size_t)(b * S + q0 + w * 32 + mt * 16 + quad * 4 + i) * D + h * 64 + l15;
#pragma unroll
        for (int d = 0; d < 4; ++d)
          op[d * 16] = __float2bfloat16(oacc[mt][d][i] * inv);
      }
    }
  }
}

// ---------------- launch ----------------
// ws layout (bf16 elements from ws16 = d_ws + 16; flag int at d_ws):
//   xb 8.4M | cosb/sinb 131k | bt_qkv 6.3M | wot 4.2M | qkv 12.6M  (~63.4 MB)
// Vt (2M elems = 4 MB) reuses bt_qkv, which is dead after the QKV GEMM.
extern "C" void kernel_launch(void* const* d_in, const int* in_sizes, int n_in,
                              void* d_out, int out_size, void* d_ws, size_t ws_size,
                              hipStream_t stream) {
  const void* x    = d_in[0];
  const void* cosp = d_in[1];
  const void* sinp = d_in[2];
  const void* wq   = d_in[3];
  const void* wk   = d_in[4];
  const void* wv   = d_in[5];
  const void* wo   = d_in[6];

  int* flag = (int*)d_ws;
  bf16* ws16 = (bf16*)((char*)d_ws + 16);
  bf16* xb     = ws16;
  bf16* cosb   = xb + (size_t)8388608;
  bf16* sinb   = cosb + 131072;
  bf16* bt_qkv = sinb + 131072;
  bf16* wot    = bt_qkv + (size_t)3072 * 2048;
  bf16* qkv    = wot + (size_t)2048 * 2048;
  bf16* o      = xb;      // x dead after QKV GEMM; attn output reuses it
  bf16* vt     = bt_qkv;  // weights dead after QKV GEMM; Vt reuses the slot

  sniff_k<<<1, 1, 0, stream>>>(cosp, flag);

  conv_k<<<(1048576 + 255) / 256, 256, 0, stream>>>(x, xb, 1048576, flag);
  conv_k<<<(16384 + 255) / 256, 256, 0, stream>>>(cosp, cosb, 16384, flag);
  conv_k<<<(16384 + 255) / 256, 256, 0, stream>>>(sinp, sinb, 16384, flag);

  dim3 tb(32, 8);
  transpose_conv_k<<<dim3(64, 64), tb, 0, stream>>>(wq, bt_qkv, 2048, flag);
  transpose_conv_k<<<dim3(16, 64), tb, 0, stream>>>(wk, bt_qkv + (size_t)2048 * 2048, 512, flag);
  transpose_conv_k<<<dim3(16, 64), tb, 0, stream>>>(wv, bt_qkv + (size_t)2560 * 2048, 512, flag);
  transpose_conv_k<<<dim3(64, 64), tb, 0, stream>>>(wo, wot, 2048, flag);

  // QKV projection: (4096,2048) @ (2048,3072), bf16 out
  gemm_bt<<<dim3(3072 / BN, 4096 / BM), 256, 0, stream>>>(xb, bt_qkv, qkv,
                                                          4096, 3072, 2048, flag, 0);

  rope_k<<<2560, 256, 0, stream>>>(qkv, cosb, sinb);

  // V pre-transpose (+bank rotation) into the dead weight slot
  vt_k<<<dim3(32, 8, 2), 256, 0, stream>>>(qkv, vt);

  // attention: 512 uniform blocks (phase pair in-block), 8x32x2 grid
  attn_k<<<dim3(8, 32, 2), 256, 0, stream>>>(qkv, vt, o);

  // output projection: (4096,2048) @ (2048,2048); output dtype follows input dtype
  gemm_bt<<<dim3(2048 / BN, 4096 / BM), 256, 0, stream>>>(o, wot, d_out,
                                                          4096, 2048, 2048, flag, 1);
}